// Round 13
// baseline (188.415 us; speedup 1.0000x reference)
//
#include <hip/hip_runtime.h>
#include <hip/hip_bf16.h>

typedef __bf16 bf16;
typedef __attribute__((ext_vector_type(2))) __bf16 bf16x2;
typedef __attribute__((ext_vector_type(4))) __bf16 bf16x4;
typedef __attribute__((ext_vector_type(8))) __bf16 bf16x8;
typedef __attribute__((ext_vector_type(4))) float f32x4;
typedef long long i64;
typedef unsigned char u8;

#define MFMA16x16x32 __builtin_amdgcn_mfma_f32_16x16x32_bf16
#define MFMA_FP8 __builtin_amdgcn_mfma_f32_16x16x32_fp8_fp8

// Problem constants
#define NB 8
#define NC 512
#define NN 4096     // H*W
#define CFG 64

#define XP 520      // LDS X row stride (bf16 elems)
#define TP 74       // LDS transpose-tile row stride

#define EXP_OFF 4.5f   // P' = exp(s - EXP_OFF): fits e4m3 range; O/l invariant

// -------------------- kernel 0: weight prep (fp32 -> bf16, concat) ----------
__global__ __launch_bounds__(256) void k_wprep(
    const float* __restrict__ Wf, const float* __restrict__ bfv,
    const float* __restrict__ Wg, const float* __restrict__ bgv,
    const float* __restrict__ Wh,
    bf16* __restrict__ Wfg, bf16* __restrict__ Whb, float* __restrict__ bfg)
{
    int idx = blockIdx.x * 256 + threadIdx.x;
    if (idx < 32768)       Wfg[idx] = (bf16)Wf[idx];
    else if (idx < 65536)  Wfg[idx] = (bf16)Wg[idx - 32768];
    if (idx < 262144)      Whb[idx] = (bf16)Wh[idx];
    if (idx < 64)          bfg[idx] = bfv[idx];
    else if (idx < 128)    bfg[idx] = bgv[idx - 64];
}

// -------------------- kernel 1: fused transpose + fg + h projections --------
// grid (8, 64): blockIdx.x = b (XCD-affinity), blockIdx.y = pixel tile (64).
// h output fp8 e4m3.
__global__ __launch_bounds__(512) void k_fused(
    const float* __restrict__ x, const bf16* __restrict__ Wfg,
    const float* __restrict__ bfg, const bf16* __restrict__ Whb,
    const float* __restrict__ bh,
    bf16* __restrict__ fF, bf16* __restrict__ gF, u8* __restrict__ hT)
{
    __shared__ bf16 X[64 * XP];       // 66,560 B
    __shared__ bf16 tile[64 * TP];    //  9,472 B

    int b = blockIdx.x, n0 = blockIdx.y * 64;
    int t = threadIdx.x;

    // ---- stage x -> X (8 chunks of 64 channels, transpose via tile) ----
    for (int cc = 0; cc < 8; cc++) {
        int cl = t >> 3, seg = (t & 7) * 8;
        const float* src = x + ((size_t)(b * NC + cc * 64 + cl)) * NN + n0 + seg;
        float4 v0 = ((const float4*)src)[0];
        float4 v1 = ((const float4*)src)[1];
        bf16* tr = &tile[cl * TP + seg];
        *(bf16x2*)(tr + 0) = bf16x2{(bf16)v0.x, (bf16)v0.y};
        *(bf16x2*)(tr + 2) = bf16x2{(bf16)v0.z, (bf16)v0.w};
        *(bf16x2*)(tr + 4) = bf16x2{(bf16)v1.x, (bf16)v1.y};
        *(bf16x2*)(tr + 6) = bf16x2{(bf16)v1.z, (bf16)v1.w};
        __syncthreads();
        int nl = t >> 3, cs = (t & 7) * 8;
        bf16 buf[8];
#pragma unroll
        for (int u = 0; u < 8; u++) buf[u] = tile[(cs + u) * TP + nl];
        *(bf16x8*)&X[nl * XP + cc * 64 + cs] = *(bf16x8*)buf;
        __syncthreads();
    }

    int w = t >> 6, l = t & 63;
    int lr = l & 15, lq = l >> 4;

    // ---- round 1: h c-tile w.  D[c][j] = Whb[c][:] . X[j][:] + bh[c] ----
    {
        const bf16* Ab = Whb + (size_t)(w * 64) * NC;
        f32x4 acc[4][4] = {};
        for (int k0 = 0; k0 < NC; k0 += 32) {
            bf16x8 a[4], bb[4];
#pragma unroll
            for (int fi = 0; fi < 4; fi++)
                a[fi] = *(const bf16x8*)(Ab + (size_t)(fi*16 + lr) * NC + k0 + lq*8);
#pragma unroll
            for (int fj = 0; fj < 4; fj++)
                bb[fj] = *(const bf16x8*)&X[(fj*16 + lr) * XP + k0 + lq*8];
#pragma unroll
            for (int fi = 0; fi < 4; fi++)
#pragma unroll
                for (int fj = 0; fj < 4; fj++)
                    acc[fi][fj] = MFMA16x16x32(a[fi], bb[fj], acc[fi][fj], 0, 0, 0);
        }
#pragma unroll
        for (int fi = 0; fi < 4; fi++)
#pragma unroll
            for (int fj = 0; fj < 4; fj++)
#pragma unroll
                for (int tt = 0; tt < 4; tt++) {
                    int c = w*64 + fi*16 + lq*4 + tt;
                    int j = n0 + fj*16 + lr;
                    float v = acc[fi][fj][tt] + bh[c];
                    int jt = j >> 6, ks = (j >> 5) & 1, lqd = (j >> 3) & 3, e = j & 7;
                    int ct = c >> 4, crd = c & 15;
                    size_t off = ((((size_t)(b*64 + jt)*32 + ct)*2 + ks)*64 + (lqd*16 + crd))*8 + e;
                    int pk = __builtin_amdgcn_cvt_pk_fp8_f32(v, v, 0, false);
                    hT[off] = (u8)pk;
                }
    }

    // ---- round 2: fg o-columns w*16..w*16+15 over all 64 pixels ----
    {
        const bf16* Bb = Wfg + (size_t)(w * 16) * NC;
        f32x4 acc2[4] = {};
        for (int k0 = 0; k0 < NC; k0 += 32) {
            bf16x8 a[4], bo;
#pragma unroll
            for (int fi = 0; fi < 4; fi++)
                a[fi] = *(const bf16x8*)&X[(fi*16 + lr) * XP + k0 + lq*8];
            bo = *(const bf16x8*)(Bb + (size_t)lr * NC + k0 + lq*8);
#pragma unroll
            for (int fi = 0; fi < 4; fi++)
                acc2[fi] = MFMA16x16x32(a[fi], bo, acc2[fi], 0, 0, 0);
        }
#pragma unroll
        for (int fi = 0; fi < 4; fi++)
#pragma unroll
            for (int tt = 0; tt < 4; tt++) {
                int n = n0 + fi*16 + lq*4 + tt;
                int o = w*16 + lr;
                float v = acc2[fi][tt] + bfg[o];
                int c = o & 63;
                bf16* dst = (o < 64) ? fF : gF;
                int jt16 = n >> 4, nr = n & 15;
                int ks = c >> 5, lqd = (c >> 3) & 3, e = c & 7;
                size_t off = (((size_t)(b*256 + jt16)*2 + ks)*64 + (lqd*16 + nr))*8 + e;
                dst[off] = (bf16)v;
            }
    }
}

// -------------------- kernel 2: fused attention (QB=128, fp8 PV) ------------
// grid (8, 32). R12 structure, but the hot loop is BRANCHLESS (last 2 phases
// peeled) so the scheduler can interleave S's chain with PV's MFMA stream.
__global__ __launch_bounds__(1024, 4) void k_attn(
    const bf16* __restrict__ fF, const bf16* __restrict__ gF,
    const u8* __restrict__ hT, const float* __restrict__ x,
    const float* __restrict__ gammap, float* __restrict__ out)
{
    __shared__ alignas(16) u8 Pl[2][2][8192];     // fp8 P: 32 KB
    __shared__ alignas(16) bf16 fS[2][8192];      // staged f (bf16): 32 KB
    __shared__ float lpart[8][2][16];
    __shared__ alignas(16) float linv[128];

    int b  = blockIdx.x;
    int i0 = blockIdx.y * 128;
    int t = threadIdx.x;
    int w = t >> 6, l = t & 63;
    int lr = l & 15, lq = l >> 4;

    float gamma = *gammap;
    int fi_s = w >> 1;     // i-16-subtile (0..7) this wave computes in S
    int ks_s = w & 1;      // j32-block this wave computes in S

    u8* Pf = &Pl[0][0][0];
    int wrA = ((fi_s*2 + ks_s)*64 + (lq >> 1)*16 + lr)*8 + (lq & 1)*4;   // byte offset

    const bf16* gbase = gF + ((size_t)(b*256 + (i0 >> 4) + fi_s)*2)*512 + (size_t)l*8;
    bf16x8 bg0 = *(const bf16x8*)(gbase);
    bf16x8 bg1 = *(const bf16x8*)(gbase + 512);

    const bf16* fb0 = fF + (size_t)b*256*2*512;
    const u8* hb0 = hT + (size_t)b*2097152 + (size_t)(w*4)*512 + (size_t)l*8;

    f32x4 oacc[8][2] = {};
    float lsum = 0.f;

#define F_LOAD(q, reg)  { (reg) = *(const bf16x8*)(fb0 + (size_t)(q)*8192 + t*8); }
#define F_WRITE(q, reg) { *(bf16x8*)&fS[(q) & 1][t*8] = (reg); }

#define S_STEP(jn, fbuf, pbuf, slot)                                           \
    {                                                                          \
        const bf16* fb = &fS[fbuf][((jn) & 1)*4096 + ks_s*2048] + l*8;         \
        bf16x8 af00 = *(const bf16x8*)(fb);                                    \
        bf16x8 af01 = *(const bf16x8*)(fb + 512);                              \
        bf16x8 af10 = *(const bf16x8*)(fb + 1024);                             \
        bf16x8 af11 = *(const bf16x8*)(fb + 1536);                             \
        f32x4 s0 = {}, s1 = {};                                                \
        s0 = MFMA16x16x32(af00, bg0, s0, 0, 0, 0);                             \
        s0 = MFMA16x16x32(af01, bg1, s0, 0, 0, 0);                             \
        s1 = MFMA16x16x32(af10, bg0, s1, 0, 0, 0);                             \
        s1 = MFMA16x16x32(af11, bg1, s1, 0, 0, 0);                             \
        float e00 = __expf(s0[0] - EXP_OFF), e01 = __expf(s0[1] - EXP_OFF);    \
        float e02 = __expf(s0[2] - EXP_OFF), e03 = __expf(s0[3] - EXP_OFF);    \
        float e10 = __expf(s1[0] - EXP_OFF), e11 = __expf(s1[1] - EXP_OFF);    \
        float e12 = __expf(s1[2] - EXP_OFF), e13 = __expf(s1[3] - EXP_OFF);    \
        lsum += (e00 + e01 + e02 + e03) + (e10 + e11 + e12 + e13);             \
        int pk0 = __builtin_amdgcn_cvt_pk_fp8_f32(e00, e01, 0, false);         \
        pk0     = __builtin_amdgcn_cvt_pk_fp8_f32(e02, e03, pk0, true);        \
        int pk1 = __builtin_amdgcn_cvt_pk_fp8_f32(e10, e11, 0, false);         \
        pk1     = __builtin_amdgcn_cvt_pk_fp8_f32(e12, e13, pk1, true);        \
        *(int*)(Pf + ((pbuf)*2 + (slot))*8192 + wrA)       = pk0;              \
        *(int*)(Pf + ((pbuf)*2 + (slot))*8192 + wrA + 256) = pk1;              \
    }

#define PV_STEP(jt, pbuf, slot)                                                \
    {                                                                          \
        const u8* hb = hb0 + (size_t)(jt) * 32768;                             \
        i64 ah00 = *(const i64*)(hb);                                          \
        i64 ah01 = *(const i64*)(hb + 512);                                    \
        i64 ah10 = *(const i64*)(hb + 1024);                                   \
        i64 ah11 = *(const i64*)(hb + 1536);                                   \
        const u8* Pr = Pf + ((pbuf)*2 + (slot))*8192 + l*8;                    \
        __builtin_amdgcn_s_setprio(1);                                         \
        _Pragma("unroll")                                                      \
        for (int fi = 0; fi < 8; fi++) {                                       \
            i64 ap0 = *(const i64*)(Pr + (fi*2 + 0)*512);                      \
            i64 ap1 = *(const i64*)(Pr + (fi*2 + 1)*512);                      \
            oacc[fi][0] = MFMA_FP8(ap0, ah00, oacc[fi][0], 0, 0, 0);           \
            oacc[fi][0] = MFMA_FP8(ap1, ah01, oacc[fi][0], 0, 0, 0);           \
            oacc[fi][1] = MFMA_FP8(ap0, ah10, oacc[fi][1], 0, 0, 0);           \
            oacc[fi][1] = MFMA_FP8(ap1, ah11, oacc[fi][1], 0, 0, 0);           \
        }                                                                      \
        __builtin_amdgcn_s_setprio(0);                                         \
    }

    // ---- prologue: stage f(0), f(1); S(0), S(1) -> P buf 0 ----
    {
        bf16x8 fr;
        F_LOAD(0, fr)
        F_WRITE(0, fr)
        __syncthreads();
        F_LOAD(1, fr)
        S_STEP(0, 0, 0, 0)
        S_STEP(1, 0, 0, 1)
        F_WRITE(1, fr)
        __syncthreads();
    }

    // ---- main loop: 30 branchless phases ----
    for (int p = 0; p < 30; p++) {
        int cur = p & 1, nxt = cur ^ 1;

        bf16x8 fr;
        F_LOAD(p + 2, fr)

        PV_STEP(2*p,     cur, 0)
        PV_STEP(2*p + 1, cur, 1)

        S_STEP(2*p + 2, nxt, nxt, 0)
        S_STEP(2*p + 3, nxt, nxt, 1)

        F_WRITE(p + 2, fr)

        __syncthreads();
    }

    // ---- tail: phase 30 (PV + S, no f staging) ----
    PV_STEP(60, 0, 0)
    PV_STEP(61, 0, 1)
    S_STEP(62, 1, 1, 0)
    S_STEP(63, 1, 1, 1)
    __syncthreads();
    // ---- tail: phase 31 (PV only) ----
    PV_STEP(62, 1, 0)
    PV_STEP(63, 1, 1)

#undef S_STEP
#undef PV_STEP
#undef F_LOAD
#undef F_WRITE

    // ---- l reduction: per-wave partials -> LDS -> linv (128 queries) ----
    lsum += __shfl_xor(lsum, 16, 64);
    lsum += __shfl_xor(lsum, 32, 64);
    if (lq == 0) lpart[fi_s][ks_s][lr] = lsum;
    __syncthreads();
    if (t < 128) {
        linv[t] = 1.0f / (lpart[t >> 4][0][t & 15] + lpart[t >> 4][1][t & 15]);
    }
    __syncthreads();

    // ---- epilogue: out = gamma * O/l + x ----
    int cw = w * 32;
    const float* xb = x + (size_t)b * NC * NN;
    float* ob = out + (size_t)b * NC * NN;
#pragma unroll
    for (int fi = 0; fi < 8; fi++) {
        f32x4 li = *(const f32x4*)&linv[fi*16 + lq*4];
#pragma unroll
        for (int fc = 0; fc < 2; fc++) {
            int c = cw + fc*16 + lr;
            size_t base = (size_t)c * NN + i0 + fi*16 + lq*4;
            float4 xv = *(const float4*)(xb + base);
            float4 ov;
            ov.x = gamma * oacc[fi][fc][0] * li[0] + xv.x;
            ov.y = gamma * oacc[fi][fc][1] * li[1] + xv.y;
            ov.z = gamma * oacc[fi][fc][2] * li[2] + xv.z;
            ov.w = gamma * oacc[fi][fc][3] * li[3] + xv.w;
            *(float4*)(ob + base) = ov;
        }
    }
}

// -------------------- launcher ----------------------------------------------
extern "C" void kernel_launch(void* const* d_in, const int* in_sizes, int n_in,
                              void* d_out, int out_size, void* d_ws, size_t ws_size,
                              hipStream_t stream)
{
    const float* x     = (const float*)d_in[0];
    const float* Wf    = (const float*)d_in[1];
    const float* bf_   = (const float*)d_in[2];
    const float* Wg    = (const float*)d_in[3];
    const float* bg_   = (const float*)d_in[4];
    const float* Wh    = (const float*)d_in[5];
    const float* bh_   = (const float*)d_in[6];
    const float* gamma = (const float*)d_in[7];
    float* out = (float*)d_out;

    char* ws = (char*)d_ws;
    u8*    hT  = (u8*)(ws + 33554432);     // fp8: 16 MB
    bf16*  fF  = (bf16*)(ws + 67108864);
    bf16*  gF  = (bf16*)(ws + 71303168);
    bf16*  Wfg = (bf16*)(ws + 75497472);
    bf16*  Whb = (bf16*)(ws + 75628544);
    float* bfg = (float*)(ws + 76152832);

    k_wprep<<<dim3(1024), dim3(256), 0, stream>>>(Wf, bf_, Wg, bg_, Wh, Wfg, Whb, bfg);
    k_fused<<<dim3(8, 64), dim3(512), 0, stream>>>(x, Wfg, bfg, Whb, bh_, fF, gF, hT);
    k_attn<<<dim3(8, 32), dim3(1024), 0, stream>>>(fF, gF, hT, x, gamma, out);
}

// Round 15
// 174.827 us; speedup vs baseline: 1.0777x; 1.0777x over previous
//
#include <hip/hip_runtime.h>
#include <hip/hip_bf16.h>

typedef __bf16 bf16;
typedef __attribute__((ext_vector_type(2))) __bf16 bf16x2;
typedef __attribute__((ext_vector_type(4))) __bf16 bf16x4;
typedef __attribute__((ext_vector_type(8))) __bf16 bf16x8;
typedef __attribute__((ext_vector_type(4))) float f32x4;
typedef __attribute__((ext_vector_type(8))) int i32x8;
typedef unsigned char u8;

#define MFMA16x16x32 __builtin_amdgcn_mfma_f32_16x16x32_bf16
// D = A*B + C, fp8 e4m3 A/B (fmt=0), K=128, per-lane E8M0 block scales
#define MFMA_MX(a, b, c, sa, sb) \
    __builtin_amdgcn_mfma_scale_f32_16x16x128_f8f6f4((a), (b), (c), 0, 0, 0, (sa), 0, (sb))

// Problem constants
#define NB 8
#define NC 512
#define NN 4096     // H*W
#define CFG 64

#define XP 520      // LDS X row stride (bf16 elems)
#define TP 74       // LDS transpose-tile row stride

#define EXP_OFF 4.5f   // P' = exp(s - EXP_OFF): fits e4m3 range; O/l invariant
#define SCALE_ONE 0x7F7F7F7F  // E8M0 1.0 in all bytes

// -------------------- kernel 0: weight prep (fp32 -> bf16, concat) ----------
__global__ __launch_bounds__(256) void k_wprep(
    const float* __restrict__ Wf, const float* __restrict__ bfv,
    const float* __restrict__ Wg, const float* __restrict__ bgv,
    const float* __restrict__ Wh,
    bf16* __restrict__ Wfg, bf16* __restrict__ Whb, float* __restrict__ bfg)
{
    int idx = blockIdx.x * 256 + threadIdx.x;
    if (idx < 32768)       Wfg[idx] = (bf16)Wf[idx];
    else if (idx < 65536)  Wfg[idx] = (bf16)Wg[idx - 32768];
    if (idx < 262144)      Whb[idx] = (bf16)Wh[idx];
    if (idx < 64)          bfg[idx] = bfv[idx];
    else if (idx < 128)    bfg[idx] = bgv[idx - 64];
}

// -------------------- kernel 1: fused transpose + fg + h projections --------
// grid (8, 64): blockIdx.x = b (XCD-affinity), blockIdx.y = pixel tile (64).
// h output fp8 e4m3 in K=128 MX fragment layout:
//   hT[b][j>>7][c>>4][lane = ((j>>5)&3)*16 + (c&15)][byte = j&31]
__global__ __launch_bounds__(512) void k_fused(
    const float* __restrict__ x, const bf16* __restrict__ Wfg,
    const float* __restrict__ bfg, const bf16* __restrict__ Whb,
    const float* __restrict__ bh,
    bf16* __restrict__ fF, bf16* __restrict__ gF, u8* __restrict__ hT)
{
    __shared__ bf16 X[64 * XP];       // 66,560 B
    __shared__ bf16 tile[64 * TP];    //  9,472 B

    int b = blockIdx.x, n0 = blockIdx.y * 64;
    int t = threadIdx.x;

    // ---- stage x -> X (8 chunks of 64 channels, transpose via tile) ----
    for (int cc = 0; cc < 8; cc++) {
        int cl = t >> 3, seg = (t & 7) * 8;
        const float* src = x + ((size_t)(b * NC + cc * 64 + cl)) * NN + n0 + seg;
        float4 v0 = ((const float4*)src)[0];
        float4 v1 = ((const float4*)src)[1];
        bf16* tr = &tile[cl * TP + seg];
        *(bf16x2*)(tr + 0) = bf16x2{(bf16)v0.x, (bf16)v0.y};
        *(bf16x2*)(tr + 2) = bf16x2{(bf16)v0.z, (bf16)v0.w};
        *(bf16x2*)(tr + 4) = bf16x2{(bf16)v1.x, (bf16)v1.y};
        *(bf16x2*)(tr + 6) = bf16x2{(bf16)v1.z, (bf16)v1.w};
        __syncthreads();
        int nl = t >> 3, cs = (t & 7) * 8;
        bf16 buf[8];
#pragma unroll
        for (int u = 0; u < 8; u++) buf[u] = tile[(cs + u) * TP + nl];
        *(bf16x8*)&X[nl * XP + cc * 64 + cs] = *(bf16x8*)buf;
        __syncthreads();
    }

    int w = t >> 6, l = t & 63;
    int lr = l & 15, lq = l >> 4;

    // ---- round 1: h c-tile w.  D[c][j] = Whb[c][:] . X[j][:] + bh[c] ----
    {
        const bf16* Ab = Whb + (size_t)(w * 64) * NC;
        f32x4 acc[4][4] = {};
        for (int k0 = 0; k0 < NC; k0 += 32) {
            bf16x8 a[4], bb[4];
#pragma unroll
            for (int fi = 0; fi < 4; fi++)
                a[fi] = *(const bf16x8*)(Ab + (size_t)(fi*16 + lr) * NC + k0 + lq*8);
#pragma unroll
            for (int fj = 0; fj < 4; fj++)
                bb[fj] = *(const bf16x8*)&X[(fj*16 + lr) * XP + k0 + lq*8];
#pragma unroll
            for (int fi = 0; fi < 4; fi++)
#pragma unroll
                for (int fj = 0; fj < 4; fj++)
                    acc[fi][fj] = MFMA16x16x32(a[fi], bb[fj], acc[fi][fj], 0, 0, 0);
        }
#pragma unroll
        for (int fi = 0; fi < 4; fi++)
#pragma unroll
            for (int fj = 0; fj < 4; fj++)
#pragma unroll
                for (int tt = 0; tt < 4; tt++) {
                    int c = w*64 + fi*16 + lq*4 + tt;
                    int j = n0 + fj*16 + lr;
                    float v = acc[fi][fj][tt] + bh[c];
                    size_t tile128 = (size_t)(b*32 + (j >> 7));
                    size_t ctile   = (size_t)(c >> 4);
                    size_t lane    = (size_t)(((j >> 5) & 3)*16 + (c & 15));
                    size_t off     = ((tile128*32 + ctile)*64 + lane)*32 + (size_t)(j & 31);
                    int pk = __builtin_amdgcn_cvt_pk_fp8_f32(v, v, 0, false);
                    hT[off] = (u8)pk;
                }
    }

    // ---- round 2: fg o-columns w*16..w*16+15 over all 64 pixels ----
    {
        const bf16* Bb = Wfg + (size_t)(w * 16) * NC;
        f32x4 acc2[4] = {};
        for (int k0 = 0; k0 < NC; k0 += 32) {
            bf16x8 a[4], bo;
#pragma unroll
            for (int fi = 0; fi < 4; fi++)
                a[fi] = *(const bf16x8*)&X[(fi*16 + lr) * XP + k0 + lq*8];
            bo = *(const bf16x8*)(Bb + (size_t)lr * NC + k0 + lq*8);
#pragma unroll
            for (int fi = 0; fi < 4; fi++)
                acc2[fi] = MFMA16x16x32(a[fi], bo, acc2[fi], 0, 0, 0);
        }
#pragma unroll
        for (int fi = 0; fi < 4; fi++)
#pragma unroll
            for (int tt = 0; tt < 4; tt++) {
                int n = n0 + fi*16 + lq*4 + tt;
                int o = w*16 + lr;
                float v = acc2[fi][tt] + bfg[o];
                int c = o & 63;
                bf16* dst = (o < 64) ? fF : gF;
                int jt16 = n >> 4, nr = n & 15;
                int ks = c >> 5, lqd = (c >> 3) & 3, e = c & 7;
                size_t off = (((size_t)(b*256 + jt16)*2 + ks)*64 + (lqd*16 + nr))*8 + e;
                dst[off] = (bf16)v;
            }
    }
}

// -------------------- kernel 2: fused attention (QB=128, MX K=128 PV) -------
// grid (8, 32). Per phase (128 keys): ONE PV pass of 16 mfma_scale K=128
// instructions (vs 64 K=32) + 2 S steps (bf16) into the next P buffer.
// P LDS: [buf][fi(8)][lane(64)][32B]; lane = (j_phase>>5)*16 + (i&15).
__global__ __launch_bounds__(1024, 4) void k_attn(
    const bf16* __restrict__ fF, const bf16* __restrict__ gF,
    const u8* __restrict__ hT, const float* __restrict__ x,
    const float* __restrict__ gammap, float* __restrict__ out)
{
    __shared__ alignas(16) u8 Pl[2][16384];       // fp8 P, MX layout: 32 KB
    __shared__ alignas(16) bf16 fS[2][8192];      // staged f (bf16): 32 KB
    __shared__ float lpart[8][2][16];
    __shared__ alignas(16) float linv[128];

    int b  = blockIdx.x;
    int i0 = blockIdx.y * 128;
    int t = threadIdx.x;
    int w = t >> 6, l = t & 63;
    int lr = l & 15, lq = l >> 4;

    float gamma = *gammap;
    int fi_s = w >> 1;     // i-16-subtile (0..7) this wave computes in S
    int ks_s = w & 1;      // j32-block this wave computes in S
    const int sone = SCALE_ONE;

    u8* Pf = &Pl[0][0];

    const bf16* gbase = gF + ((size_t)(b*256 + (i0 >> 4) + fi_s)*2)*512 + (size_t)l*8;
    bf16x8 bg0 = *(const bf16x8*)(gbase);
    bf16x8 bg1 = *(const bf16x8*)(gbase + 512);

    const bf16* fb0 = fF + (size_t)b*256*2*512;
    // hT per batch: [32 jt128][32 ct][64][32] bytes; this wave's ct base = w*2
    const u8* hb0 = hT + (size_t)b*2097152 + (size_t)(w*2)*2048 + (size_t)l*32;

    f32x4 oacc[8][2] = {};
    float lsum = 0.f;

#define F_LOAD(q, reg)  { (reg) = *(const bf16x8*)(fb0 + (size_t)(q)*8192 + t*8); }
#define F_WRITE(q, reg) { *(bf16x8*)&fS[(q) & 1][t*8] = (reg); }

    // ---- S for j-tile jn (64 keys) -> MX-layout P in Pl[pbuf] ----
#define S_STEP(jn, fbuf, pbuf)                                                 \
    {                                                                          \
        const bf16* fb = &fS[fbuf][((jn) & 1)*4096 + ks_s*2048] + l*8;         \
        bf16x8 af00 = *(const bf16x8*)(fb);                                    \
        bf16x8 af01 = *(const bf16x8*)(fb + 512);                              \
        bf16x8 af10 = *(const bf16x8*)(fb + 1024);                             \
        bf16x8 af11 = *(const bf16x8*)(fb + 1536);                             \
        f32x4 s0 = {}, s1 = {};                                                \
        s0 = MFMA16x16x32(af00, bg0, s0, 0, 0, 0);                             \
        s0 = MFMA16x16x32(af01, bg1, s0, 0, 0, 0);                             \
        s1 = MFMA16x16x32(af10, bg0, s1, 0, 0, 0);                             \
        s1 = MFMA16x16x32(af11, bg1, s1, 0, 0, 0);                             \
        float e00 = __expf(s0[0] - EXP_OFF), e01 = __expf(s0[1] - EXP_OFF);    \
        float e02 = __expf(s0[2] - EXP_OFF), e03 = __expf(s0[3] - EXP_OFF);    \
        float e10 = __expf(s1[0] - EXP_OFF), e11 = __expf(s1[1] - EXP_OFF);    \
        float e12 = __expf(s1[2] - EXP_OFF), e13 = __expf(s1[3] - EXP_OFF);    \
        lsum += (e00 + e01 + e02 + e03) + (e10 + e11 + e12 + e13);             \
        int pk0 = __builtin_amdgcn_cvt_pk_fp8_f32(e00, e01, 0, false);         \
        pk0     = __builtin_amdgcn_cvt_pk_fp8_f32(e02, e03, pk0, true);        \
        int pk1 = __builtin_amdgcn_cvt_pk_fp8_f32(e10, e11, 0, false);         \
        pk1     = __builtin_amdgcn_cvt_pk_fp8_f32(e12, e13, pk1, true);        \
        u8* pw = Pf + (pbuf)*16384 + fi_s*2048                                 \
                 + ((((jn) & 1)*2 + ks_s)*16 + lr)*32 + lq*4;                  \
        *(int*)(pw)      = pk0;                                                \
        *(int*)(pw + 16) = pk1;                                                \
    }

    // ---- PV for phase ph (128 keys) from Pl[pbuf]: 16 MX MFMAs ----
#define PV_STEP(ph, pbuf)                                                      \
    {                                                                          \
        const u8* hb = hb0 + (size_t)(ph)*65536;                               \
        i32x8 ah0 = *(const i32x8*)(hb);                                       \
        i32x8 ah1 = *(const i32x8*)(hb + 2048);                                \
        const u8* Pr = Pf + (pbuf)*16384 + l*32;                               \
        __builtin_amdgcn_s_setprio(1);                                         \
        _Pragma("unroll")                                                      \
        for (int fi = 0; fi < 8; fi++) {                                       \
            i32x8 ap = *(const i32x8*)(Pr + fi*2048);                          \
            oacc[fi][0] = MFMA_MX(ap, ah0, oacc[fi][0], sone, sone);           \
            oacc[fi][1] = MFMA_MX(ap, ah1, oacc[fi][1], sone, sone);           \
        }                                                                      \
        __builtin_amdgcn_s_setprio(0);                                         \
    }

    // ---- prologue: stage f(0), f(1); S(0), S(1) -> P buf 0 ----
    {
        bf16x8 fr;
        F_LOAD(0, fr)
        F_WRITE(0, fr)
        __syncthreads();
        F_LOAD(1, fr)
        S_STEP(0, 0, 0)
        S_STEP(1, 0, 0)
        F_WRITE(1, fr)
        __syncthreads();
    }

    // ---- main loop: 30 branchless phases ----
    for (int p = 0; p < 30; p++) {
        int cur = p & 1, nxt = cur ^ 1;

        bf16x8 fr;
        F_LOAD(p + 2, fr)

        PV_STEP(p, cur)

        S_STEP(2*p + 2, nxt, nxt)
        S_STEP(2*p + 3, nxt, nxt)

        F_WRITE(p + 2, fr)

        __syncthreads();
    }

    // ---- tail: phase 30 (PV + S, no f staging) ----
    PV_STEP(30, 0)
    S_STEP(62, 1, 1)
    S_STEP(63, 1, 1)
    __syncthreads();
    // ---- tail: phase 31 (PV only) ----
    PV_STEP(31, 1)

#undef S_STEP
#undef PV_STEP
#undef F_LOAD
#undef F_WRITE

    // ---- l reduction: per-wave partials -> LDS -> linv (128 queries) ----
    lsum += __shfl_xor(lsum, 16, 64);
    lsum += __shfl_xor(lsum, 32, 64);
    if (lq == 0) lpart[fi_s][ks_s][lr] = lsum;
    __syncthreads();
    if (t < 128) {
        linv[t] = 1.0f / (lpart[t >> 4][0][t & 15] + lpart[t >> 4][1][t & 15]);
    }
    __syncthreads();

    // ---- epilogue: out = gamma * O/l + x ----
    int cw = w * 32;
    const float* xb = x + (size_t)b * NC * NN;
    float* ob = out + (size_t)b * NC * NN;
#pragma unroll
    for (int fi = 0; fi < 8; fi++) {
        f32x4 li = *(const f32x4*)&linv[fi*16 + lq*4];
#pragma unroll
        for (int fc = 0; fc < 2; fc++) {
            int c = cw + fc*16 + lr;
            size_t base = (size_t)c * NN + i0 + fi*16 + lq*4;
            float4 xv = *(const float4*)(xb + base);
            float4 ov;
            ov.x = gamma * oacc[fi][fc][0] * li[0] + xv.x;
            ov.y = gamma * oacc[fi][fc][1] * li[1] + xv.y;
            ov.z = gamma * oacc[fi][fc][2] * li[2] + xv.z;
            ov.w = gamma * oacc[fi][fc][3] * li[3] + xv.w;
            *(float4*)(ob + base) = ov;
        }
    }
}

// -------------------- launcher ----------------------------------------------
extern "C" void kernel_launch(void* const* d_in, const int* in_sizes, int n_in,
                              void* d_out, int out_size, void* d_ws, size_t ws_size,
                              hipStream_t stream)
{
    const float* x     = (const float*)d_in[0];
    const float* Wf    = (const float*)d_in[1];
    const float* bf_   = (const float*)d_in[2];
    const float* Wg    = (const float*)d_in[3];
    const float* bg_   = (const float*)d_in[4];
    const float* Wh    = (const float*)d_in[5];
    const float* bh_   = (const float*)d_in[6];
    const float* gamma = (const float*)d_in[7];
    float* out = (float*)d_out;

    char* ws = (char*)d_ws;
    u8*    hT  = (u8*)(ws + 33554432);     // fp8: 16 MB
    bf16*  fF  = (bf16*)(ws + 67108864);
    bf16*  gF  = (bf16*)(ws + 71303168);
    bf16*  Wfg = (bf16*)(ws + 75497472);
    bf16*  Whb = (bf16*)(ws + 75628544);
    float* bfg = (float*)(ws + 76152832);

    k_wprep<<<dim3(1024), dim3(256), 0, stream>>>(Wf, bf_, Wg, bg_, Wh, Wfg, Whb, bfg);
    k_fused<<<dim3(8, 64), dim3(512), 0, stream>>>(x, Wfg, bfg, Whb, bh_, fF, gF, hT);
    k_attn<<<dim3(8, 32), dim3(1024), 0, stream>>>(fF, gF, hT, x, gamma, out);
}

// Round 16
// 165.104 us; speedup vs baseline: 1.1412x; 1.0589x over previous
//
#include <hip/hip_runtime.h>
#include <hip/hip_bf16.h>

typedef __bf16 bf16;
typedef __attribute__((ext_vector_type(2))) __bf16 bf16x2;
typedef __attribute__((ext_vector_type(4))) __bf16 bf16x4;
typedef __attribute__((ext_vector_type(8))) __bf16 bf16x8;
typedef __attribute__((ext_vector_type(4))) float f32x4;
typedef __attribute__((ext_vector_type(4))) int i32x4;
typedef __attribute__((ext_vector_type(8))) int i32x8;
typedef unsigned char u8;

#define MFMA16x16x32 __builtin_amdgcn_mfma_f32_16x16x32_bf16
// D = A*B + C, fp8 e4m3 A/B (fmt=0), K=128, per-lane E8M0 block scales
#define MFMA_MX(a, b, c, sa, sb) \
    __builtin_amdgcn_mfma_scale_f32_16x16x128_f8f6f4((a), (b), (c), 0, 0, 0, (sa), 0, (sb))

#define CAT8(lo, hi) (i32x8){(lo)[0], (lo)[1], (lo)[2], (lo)[3], (hi)[0], (hi)[1], (hi)[2], (hi)[3]}

// Problem constants
#define NB 8
#define NC 512
#define NN 4096     // H*W
#define CFG 64

#define XP 520      // LDS X row stride (bf16 elems)
#define TP 74       // LDS transpose-tile row stride

#define EXP_OFF 4.5f   // P' = exp(s - EXP_OFF): fits e4m3 range; O/l invariant
#define SCALE_ONE 0x7F7F7F7F  // E8M0 1.0 in all bytes

// -------------------- kernel 0: weight prep (fp32 -> bf16, concat) ----------
__global__ __launch_bounds__(256) void k_wprep(
    const float* __restrict__ Wf, const float* __restrict__ bfv,
    const float* __restrict__ Wg, const float* __restrict__ bgv,
    const float* __restrict__ Wh,
    bf16* __restrict__ Wfg, bf16* __restrict__ Whb, float* __restrict__ bfg)
{
    int idx = blockIdx.x * 256 + threadIdx.x;
    if (idx < 32768)       Wfg[idx] = (bf16)Wf[idx];
    else if (idx < 65536)  Wfg[idx] = (bf16)Wg[idx - 32768];
    if (idx < 262144)      Whb[idx] = (bf16)Wh[idx];
    if (idx < 64)          bfg[idx] = bfv[idx];
    else if (idx < 128)    bfg[idx] = bgv[idx - 64];
}

// -------------------- kernel 1: fused transpose + fg + h projections --------
// grid (8, 64): blockIdx.x = b (XCD-affinity), blockIdx.y = pixel tile (64).
// h output fp8 e4m3, half-split MX layout:
//   hT[b][j>>7][c>>4][hk=(j>>4)&1][lane=((j>>5)&3)*16+(c&15)][byte=j&15]
__global__ __launch_bounds__(512) void k_fused(
    const float* __restrict__ x, const bf16* __restrict__ Wfg,
    const float* __restrict__ bfg, const bf16* __restrict__ Whb,
    const float* __restrict__ bh,
    bf16* __restrict__ fF, bf16* __restrict__ gF, u8* __restrict__ hT)
{
    __shared__ bf16 X[64 * XP];       // 66,560 B
    __shared__ bf16 tile[64 * TP];    //  9,472 B

    int b = blockIdx.x, n0 = blockIdx.y * 64;
    int t = threadIdx.x;

    // ---- stage x -> X (8 chunks of 64 channels, transpose via tile) ----
    for (int cc = 0; cc < 8; cc++) {
        int cl = t >> 3, seg = (t & 7) * 8;
        const float* src = x + ((size_t)(b * NC + cc * 64 + cl)) * NN + n0 + seg;
        float4 v0 = ((const float4*)src)[0];
        float4 v1 = ((const float4*)src)[1];
        bf16* tr = &tile[cl * TP + seg];
        *(bf16x2*)(tr + 0) = bf16x2{(bf16)v0.x, (bf16)v0.y};
        *(bf16x2*)(tr + 2) = bf16x2{(bf16)v0.z, (bf16)v0.w};
        *(bf16x2*)(tr + 4) = bf16x2{(bf16)v1.x, (bf16)v1.y};
        *(bf16x2*)(tr + 6) = bf16x2{(bf16)v1.z, (bf16)v1.w};
        __syncthreads();
        int nl = t >> 3, cs = (t & 7) * 8;
        bf16 buf[8];
#pragma unroll
        for (int u = 0; u < 8; u++) buf[u] = tile[(cs + u) * TP + nl];
        *(bf16x8*)&X[nl * XP + cc * 64 + cs] = *(bf16x8*)buf;
        __syncthreads();
    }

    int w = t >> 6, l = t & 63;
    int lr = l & 15, lq = l >> 4;

    // ---- round 1: h c-tile w, computed as D[j][c] = X[j][:] . Whb[c][:] ----
    // (swapped operands so each thread holds 4 consecutive j -> 4B packed store)
    {
        const bf16* Ab = Whb + (size_t)(w * 64) * NC;
        f32x4 acc[4][4] = {};   // [fi: c-subtile][fj: j-subtile]
        for (int k0 = 0; k0 < NC; k0 += 32) {
            bf16x8 a[4], bb[4];
#pragma unroll
            for (int fi = 0; fi < 4; fi++)
                a[fi] = *(const bf16x8*)(Ab + (size_t)(fi*16 + lr) * NC + k0 + lq*8);
#pragma unroll
            for (int fj = 0; fj < 4; fj++)
                bb[fj] = *(const bf16x8*)&X[(fj*16 + lr) * XP + k0 + lq*8];
#pragma unroll
            for (int fi = 0; fi < 4; fi++)
#pragma unroll
                for (int fj = 0; fj < 4; fj++)
                    acc[fi][fj] = MFMA16x16x32(bb[fj], a[fi], acc[fi][fj], 0, 0, 0);
        }
#pragma unroll
        for (int fi = 0; fi < 4; fi++) {
            int c = w*64 + fi*16 + lr;
            float bias = bh[c];
            size_t ctile = (size_t)(c >> 4);
#pragma unroll
            for (int fj = 0; fj < 4; fj++) {
                int j0 = n0 + fj*16 + lq*4;
                float v0 = acc[fi][fj][0] + bias;
                float v1 = acc[fi][fj][1] + bias;
                float v2 = acc[fi][fj][2] + bias;
                float v3 = acc[fi][fj][3] + bias;
                int pk = __builtin_amdgcn_cvt_pk_fp8_f32(v0, v1, 0, false);
                pk     = __builtin_amdgcn_cvt_pk_fp8_f32(v2, v3, pk, true);
                size_t tile128 = (size_t)(b*32) + (size_t)(j0 >> 7);
                size_t hk   = (size_t)((j0 >> 4) & 1);
                size_t lane = (size_t)(((j0 >> 5) & 3)*16 + (c & 15));
                size_t off = ((tile128*32 + ctile)*2 + hk)*1024 + lane*16 + (size_t)(j0 & 15);
                *(int*)(hT + off) = pk;
            }
        }
    }

    // ---- round 2: fg o-columns w*16..w*16+15 over all 64 pixels ----
    {
        const bf16* Bb = Wfg + (size_t)(w * 16) * NC;
        f32x4 acc2[4] = {};
        for (int k0 = 0; k0 < NC; k0 += 32) {
            bf16x8 a[4], bo;
#pragma unroll
            for (int fi = 0; fi < 4; fi++)
                a[fi] = *(const bf16x8*)&X[(fi*16 + lr) * XP + k0 + lq*8];
            bo = *(const bf16x8*)(Bb + (size_t)lr * NC + k0 + lq*8);
#pragma unroll
            for (int fi = 0; fi < 4; fi++)
                acc2[fi] = MFMA16x16x32(a[fi], bo, acc2[fi], 0, 0, 0);
        }
#pragma unroll
        for (int fi = 0; fi < 4; fi++)
#pragma unroll
            for (int tt = 0; tt < 4; tt++) {
                int n = n0 + fi*16 + lq*4 + tt;
                int o = w*16 + lr;
                float v = acc2[fi][tt] + bfg[o];
                int c = o & 63;
                bf16* dst = (o < 64) ? fF : gF;
                int jt16 = n >> 4, nr = n & 15;
                int ks = c >> 5, lqd = (c >> 3) & 3, e = c & 7;
                size_t off = (((size_t)(b*256 + jt16)*2 + ks)*64 + (lqd*16 + nr))*8 + e;
                dst[off] = (bf16)v;
            }
    }
}

// -------------------- kernel 2: fused attention (QB=128, MX K=128 PV) -------
// grid (8, 32). Per phase (128 keys): ONE PV pass of 16 mfma_scale K=128 + 2 S
// steps. P LDS half-split: [buf][fi(8)][hk(2)][lane(64)][16B] -> all PV reads
// are lane-stride-16 b128 (conflict-free).
__global__ __launch_bounds__(1024, 4) void k_attn(
    const bf16* __restrict__ fF, const bf16* __restrict__ gF,
    const u8* __restrict__ hT, const float* __restrict__ x,
    const float* __restrict__ gammap, float* __restrict__ out)
{
    __shared__ alignas(16) u8 Pl[2][16384];       // fp8 P, half-split MX layout: 32 KB
    __shared__ alignas(16) bf16 fS[2][8192];      // staged f (bf16): 32 KB
    __shared__ float lpart[8][2][16];
    __shared__ alignas(16) float linv[128];

    int b  = blockIdx.x;
    int i0 = blockIdx.y * 128;
    int t = threadIdx.x;
    int w = t >> 6, l = t & 63;
    int lr = l & 15, lq = l >> 4;

    float gamma = *gammap;
    int fi_s = w >> 1;     // i-16-subtile (0..7) this wave computes in S
    int ks_s = w & 1;      // j32-block this wave computes in S
    const int sone = SCALE_ONE;

    u8* Pf = &Pl[0][0];

    const bf16* gbase = gF + ((size_t)(b*256 + (i0 >> 4) + fi_s)*2)*512 + (size_t)l*8;
    bf16x8 bg0 = *(const bf16x8*)(gbase);
    bf16x8 bg1 = *(const bf16x8*)(gbase + 512);

    const bf16* fb0 = fF + (size_t)b*256*2*512;
    // hT per batch: [32 jt128][32 ct][2 hk][64][16] bytes; wave ct base = w*2
    const u8* hb0 = hT + (size_t)b*2097152 + (size_t)(w*2)*2048 + (size_t)l*16;

    f32x4 oacc[8][2] = {};
    float lsum = 0.f;

#define F_LOAD(q, reg)  { (reg) = *(const bf16x8*)(fb0 + (size_t)(q)*8192 + t*8); }
#define F_WRITE(q, reg) { *(bf16x8*)&fS[(q) & 1][t*8] = (reg); }

    // ---- S for j-tile jn (64 keys) -> half-split P in Pl[pbuf] ----
#define S_STEP(jn, fbuf, pbuf)                                                 \
    {                                                                          \
        const bf16* fb = &fS[fbuf][((jn) & 1)*4096 + ks_s*2048] + l*8;         \
        bf16x8 af00 = *(const bf16x8*)(fb);                                    \
        bf16x8 af01 = *(const bf16x8*)(fb + 512);                              \
        bf16x8 af10 = *(const bf16x8*)(fb + 1024);                             \
        bf16x8 af11 = *(const bf16x8*)(fb + 1536);                             \
        f32x4 s0 = {}, s1 = {};                                                \
        s0 = MFMA16x16x32(af00, bg0, s0, 0, 0, 0);                             \
        s0 = MFMA16x16x32(af01, bg1, s0, 0, 0, 0);                             \
        s1 = MFMA16x16x32(af10, bg0, s1, 0, 0, 0);                             \
        s1 = MFMA16x16x32(af11, bg1, s1, 0, 0, 0);                             \
        float e00 = __expf(s0[0] - EXP_OFF), e01 = __expf(s0[1] - EXP_OFF);    \
        float e02 = __expf(s0[2] - EXP_OFF), e03 = __expf(s0[3] - EXP_OFF);    \
        float e10 = __expf(s1[0] - EXP_OFF), e11 = __expf(s1[1] - EXP_OFF);    \
        float e12 = __expf(s1[2] - EXP_OFF), e13 = __expf(s1[3] - EXP_OFF);    \
        lsum += (e00 + e01 + e02 + e03) + (e10 + e11 + e12 + e13);             \
        int pk0 = __builtin_amdgcn_cvt_pk_fp8_f32(e00, e01, 0, false);         \
        pk0     = __builtin_amdgcn_cvt_pk_fp8_f32(e02, e03, pk0, true);        \
        int pk1 = __builtin_amdgcn_cvt_pk_fp8_f32(e10, e11, 0, false);         \
        pk1     = __builtin_amdgcn_cvt_pk_fp8_f32(e12, e13, pk1, true);        \
        u8* pw = Pf + (pbuf)*16384 + fi_s*2048                                 \
                 + ((((jn) & 1)*2 + ks_s)*16 + lr)*16 + lq*4;                  \
        *(int*)(pw)        = pk0;                                              \
        *(int*)(pw + 1024) = pk1;                                              \
    }

    // ---- PV for phase ph (128 keys) from Pl[pbuf]: 16 MX MFMAs ----
#define PV_STEP(ph, pbuf)                                                      \
    {                                                                          \
        const u8* hb = hb0 + (size_t)(ph)*65536;                               \
        i32x4 hl0 = *(const i32x4*)(hb);                                       \
        i32x4 hh0 = *(const i32x4*)(hb + 1024);                                \
        i32x4 hl1 = *(const i32x4*)(hb + 2048);                                \
        i32x4 hh1 = *(const i32x4*)(hb + 3072);                                \
        i32x8 ah0 = CAT8(hl0, hh0);                                            \
        i32x8 ah1 = CAT8(hl1, hh1);                                            \
        const u8* Pr = Pf + (pbuf)*16384 + l*16;                               \
        __builtin_amdgcn_s_setprio(1);                                         \
        _Pragma("unroll")                                                      \
        for (int fi = 0; fi < 8; fi++) {                                       \
            i32x4 plo = *(const i32x4*)(Pr + fi*2048);                         \
            i32x4 phi = *(const i32x4*)(Pr + fi*2048 + 1024);                  \
            i32x8 ap = CAT8(plo, phi);                                         \
            oacc[fi][0] = MFMA_MX(ap, ah0, oacc[fi][0], sone, sone);           \
            oacc[fi][1] = MFMA_MX(ap, ah1, oacc[fi][1], sone, sone);           \
        }                                                                      \
        __builtin_amdgcn_s_setprio(0);                                         \
    }

    // ---- prologue: stage f(0), f(1); S(0), S(1) -> P buf 0 ----
    {
        bf16x8 fr;
        F_LOAD(0, fr)
        F_WRITE(0, fr)
        __syncthreads();
        F_LOAD(1, fr)
        S_STEP(0, 0, 0)
        S_STEP(1, 0, 0)
        F_WRITE(1, fr)
        __syncthreads();
    }

    // ---- main loop: 30 branchless phases ----
    for (int p = 0; p < 30; p++) {
        int cur = p & 1, nxt = cur ^ 1;

        bf16x8 fr;
        F_LOAD(p + 2, fr)

        PV_STEP(p, cur)

        S_STEP(2*p + 2, nxt, nxt)
        S_STEP(2*p + 3, nxt, nxt)

        F_WRITE(p + 2, fr)

        __syncthreads();
    }

    // ---- tail: phase 30 (PV + S, no f staging) ----
    PV_STEP(30, 0)
    S_STEP(62, 1, 1)
    S_STEP(63, 1, 1)
    __syncthreads();
    // ---- tail: phase 31 (PV only) ----
    PV_STEP(31, 1)

#undef S_STEP
#undef PV_STEP
#undef F_LOAD
#undef F_WRITE

    // ---- l reduction: per-wave partials -> LDS -> linv (128 queries) ----
    lsum += __shfl_xor(lsum, 16, 64);
    lsum += __shfl_xor(lsum, 32, 64);
    if (lq == 0) lpart[fi_s][ks_s][lr] = lsum;
    __syncthreads();
    if (t < 128) {
        linv[t] = 1.0f / (lpart[t >> 4][0][t & 15] + lpart[t >> 4][1][t & 15]);
    }
    __syncthreads();

    // ---- epilogue: out = gamma * O/l + x ----
    int cw = w * 32;
    const float* xb = x + (size_t)b * NC * NN;
    float* ob = out + (size_t)b * NC * NN;
#pragma unroll
    for (int fi = 0; fi < 8; fi++) {
        f32x4 li = *(const f32x4*)&linv[fi*16 + lq*4];
#pragma unroll
        for (int fc = 0; fc < 2; fc++) {
            int c = cw + fc*16 + lr;
            size_t base = (size_t)c * NN + i0 + fi*16 + lq*4;
            float4 xv = *(const float4*)(xb + base);
            float4 ov;
            ov.x = gamma * oacc[fi][fc][0] * li[0] + xv.x;
            ov.y = gamma * oacc[fi][fc][1] * li[1] + xv.y;
            ov.z = gamma * oacc[fi][fc][2] * li[2] + xv.z;
            ov.w = gamma * oacc[fi][fc][3] * li[3] + xv.w;
            *(float4*)(ob + base) = ov;
        }
    }
}

// -------------------- launcher ----------------------------------------------
extern "C" void kernel_launch(void* const* d_in, const int* in_sizes, int n_in,
                              void* d_out, int out_size, void* d_ws, size_t ws_size,
                              hipStream_t stream)
{
    const float* x     = (const float*)d_in[0];
    const float* Wf    = (const float*)d_in[1];
    const float* bf_   = (const float*)d_in[2];
    const float* Wg    = (const float*)d_in[3];
    const float* bg_   = (const float*)d_in[4];
    const float* Wh    = (const float*)d_in[5];
    const float* bh_   = (const float*)d_in[6];
    const float* gamma = (const float*)d_in[7];
    float* out = (float*)d_out;

    char* ws = (char*)d_ws;
    u8*    hT  = (u8*)(ws + 33554432);     // fp8: 16 MB
    bf16*  fF  = (bf16*)(ws + 67108864);
    bf16*  gF  = (bf16*)(ws + 71303168);
    bf16*  Wfg = (bf16*)(ws + 75497472);
    bf16*  Whb = (bf16*)(ws + 75628544);
    float* bfg = (float*)(ws + 76152832);

    k_wprep<<<dim3(1024), dim3(256), 0, stream>>>(Wf, bf_, Wg, bg_, Wh, Wfg, Whb, bfg);
    k_fused<<<dim3(8, 64), dim3(512), 0, stream>>>(x, Wfg, bfg, Whb, bh_, fF, gF, hT);
    k_attn<<<dim3(8, 32), dim3(1024), 0, stream>>>(fF, gF, hT, x, gamma, out);
}